// Round 2
// 375.146 us; speedup vs baseline: 1.1807x; 1.1807x over previous
//
#include <hip/hip_runtime.h>
#include <hip/hip_bf16.h>
#include <stdint.h>

#define HID 256
#define BOT 32

typedef short short8 __attribute__((ext_vector_type(8)));
typedef unsigned short ushort8 __attribute__((ext_vector_type(8)));
typedef float floatx4 __attribute__((ext_vector_type(4)));

// fp32 -> bf16 raw bits (truncate; ~2^-8 rel err, irrelevant at 1e-5 weight scale)
__device__ __forceinline__ unsigned short f2bu(float f) {
    return (unsigned short)(__float_as_uint(f) >> 16);
}
__device__ __forceinline__ float bu2f(unsigned short u) {
    return __uint_as_float((unsigned int)u << 16);
}
// pack 8 consecutive fp32 (two float4) into a bf16 short8 fragment
__device__ __forceinline__ short8 pack8(float4 a, float4 b) {
    short8 r;
    r[0] = (short)f2bu(a.x); r[1] = (short)f2bu(a.y);
    r[2] = (short)f2bu(a.z); r[3] = (short)f2bu(a.w);
    r[4] = (short)f2bu(b.x); r[5] = (short)f2bu(b.y);
    r[6] = (short)f2bu(b.z); r[7] = (short)f2bu(b.w);
    return r;
}

// ---------------------------------------------------------------------------
// ws layout (N=100000, E=800000 -> ~27 MB):
//   [0)              int    flags[4]  (flags[0]: edge mode; flags[1]: CSR cursor)
//   [16)             int    deg[N]
//   [16+4N)          float  dinv[N]
//   [16+8N)          int    start[N]
//   [16+12N)         int    cur[N]
//   [16+16N)         int2   srcw[E]     (src, norm-weight bits)
//   [16+16N+8E)      ushort P[N*32]     (bf16; layer-1 proj, reused as A2)
//   [16+16N+8E+64N)  ushort A1[N*32]    (bf16; layer-1 aggregate -> h1)
// ---------------------------------------------------------------------------

// int64-vs-int32 edge_index: int64 values < 2^31 have all-zero high words.
__global__ void k_detect(const int* __restrict__ ei, int* __restrict__ flags) {
    int t = threadIdx.x;           // 64 threads
    int found = 0;
    for (int i = 0; i < 8; ++i) {
        int slot = 2 * (t * 8 + i) + 1;
        if (ei[slot] != 0) found = 1;
    }
    unsigned long long b = __ballot(found);
    if (t == 0) flags[0] = (b == 0ULL) ? 1 : 0;
}

__global__ void k_deg(const int* __restrict__ ei, int E, int* __restrict__ deg,
                      const int* __restrict__ flags) {
    int mode = flags[0];
    int e = blockIdx.x * blockDim.x + threadIdx.x;
    if (e >= E) return;
    int d = mode ? ei[2 * E + 2 * e] : ei[E + e];
    atomicAdd(deg + d, 1);
}

__global__ void k_dinv(const int* __restrict__ deg, float* __restrict__ dinv, int N) {
    int i = blockIdx.x * blockDim.x + threadIdx.x;
    if (i < N) dinv[i] = rsqrtf((float)(deg[i] + 1));  // +1 self-loop
}

// Per-node CSR region allocation: block scan + one global atomic per block.
__global__ __launch_bounds__(256) void k_alloc(const int* __restrict__ deg,
                                               int* __restrict__ start,
                                               int* __restrict__ cur,
                                               int* __restrict__ cursor, int N) {
    __shared__ int sdata[256];
    __shared__ int sbase;
    int tid = threadIdx.x;
    int i = blockIdx.x * 256 + tid;
    int d = (i < N) ? deg[i] : 0;
    sdata[tid] = d;
    __syncthreads();
    for (int off = 1; off < 256; off <<= 1) {
        int t = (tid >= off) ? sdata[tid - off] : 0;
        __syncthreads();
        sdata[tid] += t;
        __syncthreads();
    }
    if (tid == 0) sbase = atomicAdd(cursor, sdata[255]);
    __syncthreads();
    if (i < N) {
        int st = sbase + sdata[tid] - d;
        start[i] = st;
        cur[i] = st;
    }
}

__global__ void k_fill(const int* __restrict__ ei, int E,
                       const float* __restrict__ dinv,
                       int* __restrict__ cur, int2* __restrict__ srcw,
                       const int* __restrict__ flags) {
    int mode = flags[0];
    int e = blockIdx.x * blockDim.x + threadIdx.x;
    if (e >= E) return;
    int s, d;
    if (mode) { s = ei[2 * e]; d = ei[2 * E + 2 * e]; }
    else      { s = ei[e];     d = ei[E + e]; }
    float w = dinv[s] * dinv[d];
    int slot = atomicAdd(cur + d, 1);
    srcw[slot] = make_int2(s, __float_as_int(w));
}

// P[n,j] = sum_k x[n,k]*Wd[j,k] via mfma 16x16x32 bf16, SWAPPED operands:
// D[j_local][n_local] -> lane holds 4 consecutive j for one node -> 8B stores.
__global__ __launch_bounds__(256) void k_gemm_down(
    const float* __restrict__ x, const float* __restrict__ Wd,
    unsigned short* __restrict__ P, int N, int nwaves)
{
    int wid  = (blockIdx.x * 256 + threadIdx.x) >> 6;
    int lane = threadIdx.x & 63;
    int m = lane & 15, q = lane >> 4;

    // A-frag (after swap): lane m holds Wd[jt*16+m][k=ks*32+q*8..+7]
    short8 bfr[2][8];
    #pragma unroll
    for (int jt = 0; jt < 2; ++jt) {
        const float4* wr = (const float4*)(Wd + (size_t)(jt * 16 + m) * HID);
        #pragma unroll
        for (int ks = 0; ks < 8; ++ks) {
            int c = (ks * 32 + q * 8) >> 2;
            bfr[jt][ks] = pack8(wr[c], wr[c + 1]);
        }
    }

    int tiles = (N + 15) >> 4;
    for (int t = wid; t < tiles; t += nwaves) {
        int n0 = t << 4;
        int row = n0 + m; if (row >= N) row = N - 1;
        const float4* xr = (const float4*)(x + (size_t)row * HID);
        floatx4 acc0 = {0.f, 0.f, 0.f, 0.f};
        floatx4 acc1 = {0.f, 0.f, 0.f, 0.f};
        #pragma unroll
        for (int ks = 0; ks < 8; ++ks) {
            int c = (ks * 32 + q * 8) >> 2;
            short8 af = pack8(xr[c], xr[c + 1]);   // B[k][n=m] = x[n0+m][k]
            acc0 = __builtin_amdgcn_mfma_f32_16x16x32_bf16(bfr[0][ks], af, acc0, 0, 0, 0);
            acc1 = __builtin_amdgcn_mfma_f32_16x16x32_bf16(bfr[1][ks], af, acc1, 0, 0, 0);
        }
        // D: col=m -> node n0+m; row=q*4+r -> j = jt*16 + q*4 + r
        if (n0 + m < N) {
            unsigned int* pr = (unsigned int*)(P + (size_t)(n0 + m) * BOT);
            uint2 v0, v1;
            v0.x = (unsigned int)f2bu(acc0[0]) | ((unsigned int)f2bu(acc0[1]) << 16);
            v0.y = (unsigned int)f2bu(acc0[2]) | ((unsigned int)f2bu(acc0[3]) << 16);
            v1.x = (unsigned int)f2bu(acc1[0]) | ((unsigned int)f2bu(acc1[1]) << 16);
            v1.y = (unsigned int)f2bu(acc1[2]) | ((unsigned int)f2bu(acc1[3]) << 16);
            *(uint2*)(pr + q * 2)     = v0;   // j = q*4..q*4+3
            *(uint2*)(pr + 8 + q * 2) = v1;   // j = 16+q*4..16+q*4+3
        }
    }
}

// Gather-aggregate over CSR: 4 threads per node, each owns 8 of 32 features.
// 16B (ushort8) gathers instead of 2B scalar: 8x fewer VMEM instructions.
__global__ __launch_bounds__(256) void k_gather(
    const unsigned short* __restrict__ feat, const float* __restrict__ dinv,
    const int* __restrict__ start, const int* __restrict__ endp,
    const int2* __restrict__ srcw, const float* __restrict__ bias,
    unsigned short* __restrict__ dst, int N, int relu_bias)
{
    int t = blockIdx.x * 256 + threadIdx.x;
    int n = t >> 2, jq = (t & 3) * 8;
    if (n >= N) return;
    float di = dinv[n];
    float w0 = di * di;
    float acc[8];
    ushort8 sv = *(const ushort8*)(feat + (size_t)n * BOT + jq);
    #pragma unroll
    for (int i = 0; i < 8; ++i) acc[i] = w0 * bu2f(sv[i]);
    int k = start[n], en = endp[n];
    for (; k + 1 < en; k += 2) {       // unroll-2: overlap record + gather latency
        int2 p0 = srcw[k];
        int2 p1 = srcw[k + 1];
        ushort8 f0 = *(const ushort8*)(feat + (size_t)p0.x * BOT + jq);
        ushort8 f1 = *(const ushort8*)(feat + (size_t)p1.x * BOT + jq);
        float wa = __int_as_float(p0.y), wb = __int_as_float(p1.y);
        #pragma unroll
        for (int i = 0; i < 8; ++i) acc[i] += wa * bu2f(f0[i]);
        #pragma unroll
        for (int i = 0; i < 8; ++i) acc[i] += wb * bu2f(f1[i]);
    }
    if (k < en) {
        int2 p = srcw[k];
        ushort8 f0 = *(const ushort8*)(feat + (size_t)p.x * BOT + jq);
        float wa = __int_as_float(p.y);
        #pragma unroll
        for (int i = 0; i < 8; ++i) acc[i] += wa * bu2f(f0[i]);
    }
    if (relu_bias) {
        #pragma unroll
        for (int i = 0; i < 8; ++i) {
            float a = acc[i] + bias[jq + i];
            acc[i] = a > 0.f ? a : 0.f;
        }
    }
    ushort8 o;
    #pragma unroll
    for (int i = 0; i < 8; ++i) o[i] = f2bu(acc[i]);
    *(ushort8*)(dst + (size_t)n * BOT + jq) = o;
}

// out[n,f] = sum_j A2[n,j]*Wup[f,j] + bu[f] + x[n,f]; K=32 = one mfma per tile.
// SWAPPED operands: D[f_local][n_local] -> lane holds 4 consecutive f for one
// node -> float4 x-load + 16B nontemporal out-store per ft-tile.
__global__ __launch_bounds__(256) void k_out(
    const unsigned short* __restrict__ A2, const float* __restrict__ x,
    const float* __restrict__ Wup, const float* __restrict__ bup,
    float* __restrict__ out, int N, int nwaves)
{
    int wid  = (blockIdx.x * 256 + threadIdx.x) >> 6;
    int lane = threadIdx.x & 63;
    int m = lane & 15, q = lane >> 4;

    // A-frag (after swap): lane m holds Wup[ft*16+m][j=q*8..+7]
    short8 bfr[16];
    #pragma unroll
    for (int ft = 0; ft < 16; ++ft) {
        const float4* wr = (const float4*)(Wup + (size_t)(ft * 16 + m) * BOT);
        bfr[ft] = pack8(wr[q * 2], wr[q * 2 + 1]);
    }

    int tiles = (N + 15) >> 4;
    for (int t = wid; t < tiles; t += nwaves) {
        int n0 = t << 4;
        int arow = n0 + m; if (arow >= N) arow = N - 1;
        short8 af = *(const short8*)(A2 + (size_t)arow * BOT + q * 8);  // B[k][n=m]
        const float4* xrow = (const float4*)(x + (size_t)arow * HID);
        floatx4* orow = (floatx4*)(out + (size_t)arow * HID);
        bool ok = (n0 + m) < N;
        #pragma unroll
        for (int ft = 0; ft < 16; ++ft) {
            floatx4 acc = {0.f, 0.f, 0.f, 0.f};
            acc = __builtin_amdgcn_mfma_f32_16x16x32_bf16(bfr[ft], af, acc, 0, 0, 0);
            // D: col=m -> node n0+m; row=q*4+r -> f = ft*16 + q*4 + r
            if (ok) {
                int c = ft * 4 + q;                      // float4 index in row
                float4 xv = xrow[c];
                float4 bb = *(const float4*)(bup + ft * 16 + q * 4);
                floatx4 res;
                res[0] = acc[0] + bb.x + xv.x;
                res[1] = acc[1] + bb.y + xv.y;
                res[2] = acc[2] + bb.z + xv.z;
                res[3] = acc[3] + bb.w + xv.w;
                __builtin_nontemporal_store(res, &orow[c]);
            }
        }
    }
}

extern "C" void kernel_launch(void* const* d_in, const int* in_sizes, int n_in,
                              void* d_out, int out_size, void* d_ws, size_t ws_size,
                              hipStream_t stream) {
    const float* x  = (const float*)d_in[0];
    const int*   ei = (const int*)d_in[1];
    const float* Wd = (const float*)d_in[2];
    const float* bd = (const float*)d_in[3];
    const float* Wu = (const float*)d_in[4];
    const float* bu = (const float*)d_in[5];
    float* out = (float*)d_out;

    int N = in_sizes[0] / HID;   // 100000
    int E = in_sizes[1] / 2;     // 800000

    char* ws = (char*)d_ws;
    int*   flags = (int*)ws;                                  // flags[1] = CSR cursor
    int*   deg   = (int*)(ws + 16);
    float* dinv  = (float*)(ws + 16 + (size_t)N * 4);
    int*   startp= (int*)(ws + 16 + (size_t)N * 8);
    int*   curp  = (int*)(ws + 16 + (size_t)N * 12);
    int2*  srcw  = (int2*)(ws + 16 + (size_t)N * 16);
    unsigned short* P  = (unsigned short*)(ws + 16 + (size_t)N * 16 + (size_t)E * 8);
    unsigned short* A1 = (unsigned short*)(ws + 16 + (size_t)N * 16 + (size_t)E * 8 + (size_t)N * 64);

    (void)hipMemsetAsync(ws, 0, 16 + (size_t)N * 4, stream);  // flags + cursor + deg
    k_detect<<<1, 64, 0, stream>>>(ei, flags);
    k_deg<<<(E + 255) / 256, 256, 0, stream>>>(ei, E, deg, flags);
    k_dinv<<<(N + 255) / 256, 256, 0, stream>>>(deg, dinv, N);

    // CSR build (destination-ordered)
    k_alloc<<<(N + 255) / 256, 256, 0, stream>>>(deg, startp, curp, flags + 1, N);
    k_fill<<<(E + 255) / 256, 256, 0, stream>>>(ei, E, dinv, curp, srcw, flags);

    // Layer 1: P = x @ Wd^T (MFMA) ; h1 = relu(gather(P) + bd)
    // 782 blocks = 3128 waves: 6250 tiles -> ~2 tiles/wave, near-perfect balance.
    int gblocks = 782;
    k_gemm_down<<<gblocks, 256, 0, stream>>>(x, Wd, P, N, gblocks * 4);
    int gthreads = N * 4;   // 4 threads per node
    k_gather<<<(gthreads + 255) / 256, 256, 0, stream>>>(P, dinv, startp, curp, srcw, bd, A1, N, 1);

    // Layer 2: A2 = gather(h1)  (reuses P buffer)
    k_gather<<<(gthreads + 255) / 256, 256, 0, stream>>>(A1, dinv, startp, curp, srcw, bd, P, N, 0);

    // out = A2 @ Wu^T + bu + x  (MFMA epilogue-fused)
    int oblocks = 782;
    k_out<<<oblocks, 256, 0, stream>>>(P, x, Wu, bu, out, N, oblocks * 4);
}

// Round 3
// 360.122 us; speedup vs baseline: 1.2300x; 1.0417x over previous
//
#include <hip/hip_runtime.h>
#include <hip/hip_bf16.h>
#include <stdint.h>

#define HID 256
#define BOT 32

typedef short short8 __attribute__((ext_vector_type(8)));
typedef unsigned short ushort8 __attribute__((ext_vector_type(8)));
typedef float floatx4 __attribute__((ext_vector_type(4)));

// fp32 -> bf16 raw bits (truncate; ~2^-8 rel err, irrelevant at 1e-5 weight scale)
__device__ __forceinline__ unsigned short f2bu(float f) {
    return (unsigned short)(__float_as_uint(f) >> 16);
}
__device__ __forceinline__ float bu2f(unsigned short u) {
    return __uint_as_float((unsigned int)u << 16);
}
// pack 8 consecutive fp32 (two float4) into a bf16 short8 fragment
__device__ __forceinline__ short8 pack8(float4 a, float4 b) {
    short8 r;
    r[0] = (short)f2bu(a.x); r[1] = (short)f2bu(a.y);
    r[2] = (short)f2bu(a.z); r[3] = (short)f2bu(a.w);
    r[4] = (short)f2bu(b.x); r[5] = (short)f2bu(b.y);
    r[6] = (short)f2bu(b.z); r[7] = (short)f2bu(b.w);
    return r;
}

// ---------------------------------------------------------------------------
// ws layout (N=100000, E=800000 -> ~27 MB):
//   [0)              int    flags[4]  (flags[0]: edge mode; flags[1]: CSR cursor)
//   [16)             int    deg[N]
//   [16+4N)          float  dinv[N]
//   [16+8N)          int    start[N]
//   [16+12N)         int    cur[N]
//   [16+16N)         int2   srcw[E]     (src, norm-weight bits)
//   [16+16N+8E)      ushort P[N*32]     (bf16; layer-1 proj, reused as A2)
//   [16+16N+8E+64N)  ushort A1[N*32]    (bf16; layer-1 aggregate -> h1)
// ---------------------------------------------------------------------------

// int64-vs-int32 edge_index: int64 values < 2^31 have all-zero high words.
__global__ void k_detect(const int* __restrict__ ei, int* __restrict__ flags) {
    int t = threadIdx.x;           // 64 threads
    int found = 0;
    for (int i = 0; i < 8; ++i) {
        int slot = 2 * (t * 8 + i) + 1;
        if (ei[slot] != 0) found = 1;
    }
    unsigned long long b = __ballot(found);
    if (t == 0) flags[0] = (b == 0ULL) ? 1 : 0;
}

__global__ void k_deg(const int* __restrict__ ei, int E, int* __restrict__ deg,
                      const int* __restrict__ flags) {
    int mode = flags[0];
    int e = blockIdx.x * blockDim.x + threadIdx.x;
    if (e >= E) return;
    int d = mode ? ei[2 * E + 2 * e] : ei[E + e];
    atomicAdd(deg + d, 1);
}

// Per-node CSR region allocation (block scan + one global atomic) + dinv fused.
__global__ __launch_bounds__(256) void k_alloc(const int* __restrict__ deg,
                                               float* __restrict__ dinv,
                                               int* __restrict__ start,
                                               int* __restrict__ cur,
                                               int* __restrict__ cursor, int N) {
    __shared__ int sdata[256];
    __shared__ int sbase;
    int tid = threadIdx.x;
    int i = blockIdx.x * 256 + tid;
    int d = (i < N) ? deg[i] : 0;
    if (i < N) dinv[i] = rsqrtf((float)(d + 1));  // +1 self-loop
    sdata[tid] = d;
    __syncthreads();
    for (int off = 1; off < 256; off <<= 1) {
        int t = (tid >= off) ? sdata[tid - off] : 0;
        __syncthreads();
        sdata[tid] += t;
        __syncthreads();
    }
    if (tid == 0) sbase = atomicAdd(cursor, sdata[255]);
    __syncthreads();
    if (i < N) {
        int st = sbase + sdata[tid] - d;
        start[i] = st;
        cur[i] = st;
    }
}

__global__ void k_fill(const int* __restrict__ ei, int E,
                       const float* __restrict__ dinv,
                       int* __restrict__ cur, int2* __restrict__ srcw,
                       const int* __restrict__ flags) {
    int mode = flags[0];
    int e = blockIdx.x * blockDim.x + threadIdx.x;
    if (e >= E) return;
    int s, d;
    if (mode) { s = ei[2 * e]; d = ei[2 * E + 2 * e]; }
    else      { s = ei[e];     d = ei[E + e]; }
    float w = dinv[s] * dinv[d];
    int slot = atomicAdd(cur + d, 1);
    srcw[slot] = make_int2(s, __float_as_int(w));
}

// P[n,j] = sum_k x[n,k]*Wd[j,k] via mfma 16x16x32 bf16, SWAPPED operands:
// D[j_local][n_local] -> lane holds 4 consecutive j for one node -> 8B stores.
__global__ __launch_bounds__(256) void k_gemm_down(
    const float* __restrict__ x, const float* __restrict__ Wd,
    unsigned short* __restrict__ P, int N, int nwaves)
{
    int wid  = (blockIdx.x * 256 + threadIdx.x) >> 6;
    int lane = threadIdx.x & 63;
    int m = lane & 15, q = lane >> 4;

    // A-frag (after swap): lane m holds Wd[jt*16+m][k=ks*32+q*8..+7]
    short8 bfr[2][8];
    #pragma unroll
    for (int jt = 0; jt < 2; ++jt) {
        const float4* wr = (const float4*)(Wd + (size_t)(jt * 16 + m) * HID);
        #pragma unroll
        for (int ks = 0; ks < 8; ++ks) {
            int c = (ks * 32 + q * 8) >> 2;
            bfr[jt][ks] = pack8(wr[c], wr[c + 1]);
        }
    }

    int tiles = (N + 15) >> 4;
    for (int t = wid; t < tiles; t += nwaves) {
        int n0 = t << 4;
        int row = n0 + m; if (row >= N) row = N - 1;
        const float4* xr = (const float4*)(x + (size_t)row * HID);
        floatx4 acc0 = {0.f, 0.f, 0.f, 0.f};
        floatx4 acc1 = {0.f, 0.f, 0.f, 0.f};
        #pragma unroll
        for (int ks = 0; ks < 8; ++ks) {
            int c = (ks * 32 + q * 8) >> 2;
            short8 af = pack8(xr[c], xr[c + 1]);   // B[k][n=m] = x[n0+m][k]
            acc0 = __builtin_amdgcn_mfma_f32_16x16x32_bf16(bfr[0][ks], af, acc0, 0, 0, 0);
            acc1 = __builtin_amdgcn_mfma_f32_16x16x32_bf16(bfr[1][ks], af, acc1, 0, 0, 0);
        }
        // D: col=m -> node n0+m; row=q*4+r -> j = jt*16 + q*4 + r
        if (n0 + m < N) {
            unsigned int* pr = (unsigned int*)(P + (size_t)(n0 + m) * BOT);
            uint2 v0, v1;
            v0.x = (unsigned int)f2bu(acc0[0]) | ((unsigned int)f2bu(acc0[1]) << 16);
            v0.y = (unsigned int)f2bu(acc0[2]) | ((unsigned int)f2bu(acc0[3]) << 16);
            v1.x = (unsigned int)f2bu(acc1[0]) | ((unsigned int)f2bu(acc1[1]) << 16);
            v1.y = (unsigned int)f2bu(acc1[2]) | ((unsigned int)f2bu(acc1[3]) << 16);
            *(uint2*)(pr + q * 2)     = v0;   // j = q*4..q*4+3
            *(uint2*)(pr + 8 + q * 2) = v1;   // j = 16+q*4..16+q*4+3
        }
    }
}

// Gather-aggregate over CSR: 4 threads per node, each owns 8 of 32 features.
// Inner loop: 4 edges/iter; each lane of the 4-lane group loads ONE srcw record,
// broadcast via __shfl(width=4) -> 1/4 the srcw VMEM ops, 4 gathers in flight.
__global__ __launch_bounds__(256) void k_gather(
    const unsigned short* __restrict__ feat, const float* __restrict__ dinv,
    const int* __restrict__ start, const int* __restrict__ endp,
    const int2* __restrict__ srcw, const float* __restrict__ bias,
    unsigned short* __restrict__ dst, int N, int relu_bias)
{
    int t = blockIdx.x * 256 + threadIdx.x;
    int n = t >> 2, tg = t & 3, jq = tg * 8;
    if (n >= N) return;
    float di = dinv[n];
    float w0 = di * di;
    float acc[8];
    ushort8 sv = *(const ushort8*)(feat + (size_t)n * BOT + jq);
    #pragma unroll
    for (int i = 0; i < 8; ++i) acc[i] = w0 * bu2f(sv[i]);
    int k = start[n], en = endp[n];
    for (; k < en; k += 4) {
        int kk = k + tg;
        int2 p = make_int2(0, 0);          // src=0 w=0 for tail lanes (adds 0)
        if (kk < en) p = srcw[kk];
        #pragma unroll
        for (int e = 0; e < 4; ++e) {
            int   src = __shfl(p.x, e, 4);
            float w   = __uint_as_float((unsigned int)__shfl(p.y, e, 4));
            ushort8 f = *(const ushort8*)(feat + (size_t)src * BOT + jq);
            #pragma unroll
            for (int i = 0; i < 8; ++i) acc[i] += w * bu2f(f[i]);
        }
    }
    if (relu_bias) {
        #pragma unroll
        for (int i = 0; i < 8; ++i) {
            float a = acc[i] + bias[jq + i];
            acc[i] = a > 0.f ? a : 0.f;
        }
    }
    ushort8 o;
    #pragma unroll
    for (int i = 0; i < 8; ++i) o[i] = f2bu(acc[i]);
    *(ushort8*)(dst + (size_t)n * BOT + jq) = o;
}

// out[n,f] = sum_j A2[n,j]*Wup[f,j] + bu[f] + x[n,f].
// SWAPPED operands: lane holds 4 consecutive f for one node -> float4 x-load +
// 16B nontemporal out-store per ft-tile. TWO waves per 16-node tile (8 ft each)
// -> 12500 waves for MLP; Wup/bias loads are L2-hot (32KB table).
__global__ __launch_bounds__(256) void k_out(
    const unsigned short* __restrict__ A2, const float* __restrict__ x,
    const float* __restrict__ Wup, const float* __restrict__ bup,
    float* __restrict__ out, int N)
{
    int gw   = (blockIdx.x * 256 + threadIdx.x) >> 6;
    int lane = threadIdx.x & 63;
    int m = lane & 15, q = lane >> 4;
    int tiles = (N + 15) >> 4;
    int t = gw >> 1, h = gw & 1;
    if (t >= tiles) return;

    int n0 = t << 4;
    int arow = n0 + m; if (arow >= N) arow = N - 1;
    short8 af = *(const short8*)(A2 + (size_t)arow * BOT + q * 8);  // B[k][n=m]
    const float4* xrow = (const float4*)(x + (size_t)arow * HID);
    floatx4* orow = (floatx4*)(out + (size_t)arow * HID);
    bool ok = (n0 + m) < N;
    #pragma unroll
    for (int i = 0; i < 8; ++i) {
        int ft = h * 8 + i;
        const float4* wr = (const float4*)(Wup + (size_t)(ft * 16 + m) * BOT);
        short8 bfr = pack8(wr[q * 2], wr[q * 2 + 1]);
        floatx4 acc = {0.f, 0.f, 0.f, 0.f};
        acc = __builtin_amdgcn_mfma_f32_16x16x32_bf16(bfr, af, acc, 0, 0, 0);
        // D: col=m -> node n0+m; row=q*4+r -> f = ft*16 + q*4 + r
        if (ok) {
            int c = ft * 4 + q;                      // float4 index in row
            float4 xv = xrow[c];
            float4 bb = *(const float4*)(bup + ft * 16 + q * 4);
            floatx4 res;
            res[0] = acc[0] + bb.x + xv.x;
            res[1] = acc[1] + bb.y + xv.y;
            res[2] = acc[2] + bb.z + xv.z;
            res[3] = acc[3] + bb.w + xv.w;
            __builtin_nontemporal_store(res, &orow[c]);
        }
    }
}

extern "C" void kernel_launch(void* const* d_in, const int* in_sizes, int n_in,
                              void* d_out, int out_size, void* d_ws, size_t ws_size,
                              hipStream_t stream) {
    const float* x  = (const float*)d_in[0];
    const int*   ei = (const int*)d_in[1];
    const float* Wd = (const float*)d_in[2];
    const float* bd = (const float*)d_in[3];
    const float* Wu = (const float*)d_in[4];
    const float* bu = (const float*)d_in[5];
    float* out = (float*)d_out;

    int N = in_sizes[0] / HID;   // 100000
    int E = in_sizes[1] / 2;     // 800000

    char* ws = (char*)d_ws;
    int*   flags = (int*)ws;                                  // flags[1] = CSR cursor
    int*   deg   = (int*)(ws + 16);
    float* dinv  = (float*)(ws + 16 + (size_t)N * 4);
    int*   startp= (int*)(ws + 16 + (size_t)N * 8);
    int*   curp  = (int*)(ws + 16 + (size_t)N * 12);
    int2*  srcw  = (int2*)(ws + 16 + (size_t)N * 16);
    unsigned short* P  = (unsigned short*)(ws + 16 + (size_t)N * 16 + (size_t)E * 8);
    unsigned short* A1 = (unsigned short*)(ws + 16 + (size_t)N * 16 + (size_t)E * 8 + (size_t)N * 64);

    (void)hipMemsetAsync(ws, 0, 16 + (size_t)N * 4, stream);  // flags + cursor + deg
    k_detect<<<1, 64, 0, stream>>>(ei, flags);
    k_deg<<<(E + 255) / 256, 256, 0, stream>>>(ei, E, deg, flags);

    // CSR build (destination-ordered); dinv fused into alloc
    k_alloc<<<(N + 255) / 256, 256, 0, stream>>>(deg, dinv, startp, curp, flags + 1, N);
    k_fill<<<(E + 255) / 256, 256, 0, stream>>>(ei, E, dinv, curp, srcw, flags);

    // Layer 1: P = x @ Wd^T (MFMA) ; h1 = relu(gather(P) + bd)
    int tiles = (N + 15) / 16;                  // 6250
    int gblocks = (tiles + 3) / 4;              // 1 tile per wave
    k_gemm_down<<<gblocks, 256, 0, stream>>>(x, Wd, P, N, gblocks * 4);
    int gthreads = N * 4;   // 4 threads per node
    k_gather<<<(gthreads + 255) / 256, 256, 0, stream>>>(P, dinv, startp, curp, srcw, bd, A1, N, 1);

    // Layer 2: A2 = gather(h1)  (reuses P buffer)
    k_gather<<<(gthreads + 255) / 256, 256, 0, stream>>>(A1, dinv, startp, curp, srcw, bd, P, N, 0);

    // out = A2 @ Wu^T + bu + x  (MFMA epilogue-fused), 2 waves per tile
    int oblocks = (tiles * 2 + 3) / 4;          // 3125
    k_out<<<oblocks, 256, 0, stream>>>(P, x, Wu, bu, out, N);
}